// Round 6
// baseline (468.214 us; speedup 1.0000x reference)
//
#include <hip/hip_runtime.h>
#include <stdint.h>

#define N_NODES 100000
#define N_EDGES 1600000
#define IN_DIM 32
#define OUT_DIM 64
#define N_REL 8
#define NSEG (N_NODES * N_REL)     // 800000
#define EPS 1e-10f
#define N_KK 9                      // K-tiles of 32 (8 rel + 1 self)
#define SCAN_BS 1024                // elems per scan block
#define NBLK ((NSEG + SCAN_BS - 1) / SCAN_BS)  // 782

typedef __attribute__((ext_vector_type(8))) short bf16x8;
typedef __attribute__((ext_vector_type(4))) float f32x4;

static __device__ __forceinline__ float bflo(uint32_t u) { return __uint_as_float(u << 16); }
static __device__ __forceinline__ uint16_t f2bf(float f) {
    uint32_t u = __float_as_uint(f);
    return (uint16_t)((u + 0x7fffu + ((u >> 16) & 1u)) >> 16); // RNE
}

// ---------------------------------------------------------------------------
// Dtype probe (round-3 proved fp32; kept for robustness, ~3us).
// ---------------------------------------------------------------------------
__global__ __launch_bounds__(256) void detect_kernel(const uint32_t* __restrict__ xw,
                                                     int* __restrict__ flag) {
    __shared__ int cnt;
    if (threadIdx.x == 0) cnt = 0;
    __syncthreads();
    int c = 0;
    for (int k = threadIdx.x; k < 4096; k += 256) {
        uint32_t w = xw[k];
        uint32_t e = (w >> 7) & 0xffu;
        c += (e >= 160u) ? 1 : 0;
    }
    atomicAdd(&cnt, c);
    __syncthreads();
    if (threadIdx.x == 0) *flag = (cnt > 64) ? 1 : 0;  // 1 = fp32 inputs
}

// ---------------------------------------------------------------------------
// 1) histogram: hist[dst*8+rel]++ (int atomics, 16x fewer than fp32 scatter)
// ---------------------------------------------------------------------------
__global__ __launch_bounds__(256) void hist_kernel(const int* __restrict__ el,
                                                   unsigned int* __restrict__ hist) {
    int e = blockIdx.x * 256 + threadIdx.x;
    if (e >= N_EDGES) return;
    int dst = el[e * 3 + 1];
    int rel = el[e * 3 + 2];
    atomicAdd(&hist[dst * N_REL + rel], 1u);
}

// ---------------------------------------------------------------------------
// 2a) per-block inclusive scan (1024 elems / block), block totals to bsum
// ---------------------------------------------------------------------------
__global__ __launch_bounds__(256) void scanA_kernel(unsigned int* __restrict__ hist,
                                                    unsigned int* __restrict__ bsum) {
    __shared__ unsigned int lds[256];
    int t = threadIdx.x;
    int base = blockIdx.x * SCAN_BS + t * 4;
    unsigned int v[4];
    #pragma unroll
    for (int k = 0; k < 4; ++k) {
        int i = base + k;
        v[k] = (i < NSEG) ? hist[i] : 0u;
    }
    v[1] += v[0]; v[2] += v[1]; v[3] += v[2];   // local inclusive
    lds[t] = v[3];
    __syncthreads();
    unsigned int xv = lds[t];
    for (int off = 1; off < 256; off <<= 1) {
        unsigned int add = (t >= off) ? lds[t - off] : 0u;
        __syncthreads();
        xv += add;
        lds[t] = xv;
        __syncthreads();
    }
    unsigned int excl = (t == 0) ? 0u : lds[t - 1];
    #pragma unroll
    for (int k = 0; k < 4; ++k) {
        int i = base + k;
        if (i < NSEG) hist[i] = excl + v[k];
    }
    if (t == 255) bsum[blockIdx.x] = lds[255];
}

// ---------------------------------------------------------------------------
// 2b) single-block EXCLUSIVE scan of block totals (NBLK <= 1024)
// ---------------------------------------------------------------------------
__global__ __launch_bounds__(256) void scanB_kernel(unsigned int* __restrict__ bsum) {
    __shared__ unsigned int lds[256];
    int t = threadIdx.x;
    int base = t * 4;
    unsigned int v[4];
    #pragma unroll
    for (int k = 0; k < 4; ++k) v[k] = (base + k < NBLK) ? bsum[base + k] : 0u;
    unsigned int l0 = v[0], l1 = l0 + v[1], l2 = l1 + v[2], l3 = l2 + v[3];
    lds[t] = l3;
    __syncthreads();
    unsigned int xv = lds[t];
    for (int off = 1; off < 256; off <<= 1) {
        unsigned int add = (t >= off) ? lds[t - off] : 0u;
        __syncthreads();
        xv += add;
        lds[t] = xv;
        __syncthreads();
    }
    unsigned int excl = (t == 0) ? 0u : lds[t - 1];
    if (base + 0 < NBLK) bsum[base + 0] = excl;
    if (base + 1 < NBLK) bsum[base + 1] = excl + l0;
    if (base + 2 < NBLK) bsum[base + 2] = excl + l1;
    if (base + 3 < NBLK) bsum[base + 3] = excl + l2;
}

// ---------------------------------------------------------------------------
// 2c) add block offsets -> hist[seg] = global inclusive scan = segment END
// ---------------------------------------------------------------------------
__global__ __launch_bounds__(256) void scanC_kernel(unsigned int* __restrict__ hist,
                                                    const unsigned int* __restrict__ bsum) {
    int i = blockIdx.x * 256 + threadIdx.x;
    if (i >= NSEG) return;
    hist[i] += bsum[i >> 10];
}

// ---------------------------------------------------------------------------
// 3) reorder: pos = --hist[seg]; epack[pos] = (w_bits<<32)|src.
//    Destructive sub leaves hist[seg] = segment START for the accum pass.
// ---------------------------------------------------------------------------
__global__ __launch_bounds__(256) void reorder_kernel(const int* __restrict__ el,
                                                      const void* __restrict__ ew,
                                                      const int* __restrict__ flag,
                                                      unsigned int* __restrict__ hist,
                                                      uint64_t* __restrict__ epack) {
    int e = blockIdx.x * 256 + threadIdx.x;
    if (e >= N_EDGES) return;
    int src = el[e * 3 + 0];
    int dst = el[e * 3 + 1];
    int rel = el[e * 3 + 2];
    uint32_t wb = (*flag) ? ((const uint32_t*)ew)[e]
                          : (((uint32_t)((const uint16_t*)ew)[e]) << 16);
    unsigned int pos = atomicSub(&hist[dst * N_REL + rel], 1u) - 1u;
    epack[pos] = ((uint64_t)wb << 32) | (uint32_t)src;
}

// ---------------------------------------------------------------------------
// 4) accumulate per segment, divide, store A as bf16 (pre-divided, row-major):
//    A[seg*32+i] = f2bf( sum_e w*x[src,i] / (sum_e w + eps) )
//    Thread (seg,i): 8 segs/block. No atomics, coalesced 64B stores.
// ---------------------------------------------------------------------------
__global__ __launch_bounds__(256) void accum_kernel(const uint64_t* __restrict__ epack,
                                                    const unsigned int* __restrict__ hist,
                                                    const void* __restrict__ x,
                                                    const int* __restrict__ flag,
                                                    uint16_t* __restrict__ A) {
    int seg = blockIdx.x * 8 + (threadIdx.x >> 5);
    int i = threadIdx.x & 31;
    unsigned int start = hist[seg];
    unsigned int end = (seg == NSEG - 1) ? (unsigned int)N_EDGES : hist[seg + 1];
    int f32 = *flag;

    float acc = 0.0f, wsum = 0.0f;
    for (unsigned int e = start; e < end; ++e) {
        uint64_t p = epack[e];                       // broadcast across 32 lanes
        uint32_t src = (uint32_t)p;
        float w = __uint_as_float((uint32_t)(p >> 32));
        float xv = f32 ? ((const float*)x)[(size_t)src * IN_DIM + i]
                       : bflo((uint32_t)((const uint16_t*)x)[(size_t)src * IN_DIM + i]);
        acc += w * xv;
        wsum += w;
    }
    A[(size_t)seg * IN_DIM + i] = f2bf(acc / (wsum + EPS));
}

// ---------------------------------------------------------------------------
// 5) dense MFMA GEMM (round-5 structure): C[100000x64] = [A | x] * [Wl ; Ws]
//    A-operand: one bf16x8 global load per K-step (pre-divided bf16).
// ---------------------------------------------------------------------------
__global__ __launch_bounds__(256) void dense_mfma_kernel(
    const uint16_t* __restrict__ A,
    const void* __restrict__ x,
    const void* __restrict__ Wl,
    const void* __restrict__ bl,
    const void* __restrict__ Ws,
    const void* __restrict__ bs,
    const int* __restrict__ flag,
    void* __restrict__ out)
{
    __shared__ uint16_t sB[N_KK * 4 * 64 * 8]; // 18432 bf16 = 36KB
    int f32 = *flag;

    for (int idx = threadIdx.x; idx < N_KK * 4 * 64 * 8; idx += 256) {
        int j    = idx & 7;
        int lane = (idx >> 3) & 63;
        int ot   = (idx >> 9) & 3;
        int kk   = idx >> 11;
        int quad = lane >> 4;
        int k = kk * 32 + quad * 8 + j;
        int o = ot * 16 + (lane & 15);
        if (f32) {
            float v = (k < 256) ? ((const float*)Wl)[(size_t)k * OUT_DIM + o]
                                : ((const float*)Ws)[(size_t)(k - 256) * OUT_DIM + o];
            sB[idx] = f2bf(v);
        } else {
            sB[idx] = (k < 256) ? ((const uint16_t*)Wl)[(size_t)k * OUT_DIM + o]
                                : ((const uint16_t*)Ws)[(size_t)(k - 256) * OUT_DIM + o];
        }
    }
    __syncthreads();

    int wid  = threadIdx.x >> 6;
    int lane = threadIdx.x & 63;
    int quad = lane >> 4;
    int m    = lane & 15;

    int n0 = blockIdx.x * 64 + wid * 16;
    int n  = n0 + m;
    int nc = (n < N_NODES) ? n : (N_NODES - 1);

    float bias[4];
    #pragma unroll
    for (int ot = 0; ot < 4; ++ot) {
        int o = ot * 16 + m;
        if (f32) bias[ot] = ((const float*)bl)[o] + ((const float*)bs)[o];
        else     bias[ot] = bflo((uint32_t)((const uint16_t*)bl)[o])
                          + bflo((uint32_t)((const uint16_t*)bs)[o]);
    }

    f32x4 acc[4];
    #pragma unroll
    for (int ot = 0; ot < 4; ++ot) acc[ot] = (f32x4){0.f, 0.f, 0.f, 0.f};

    #pragma unroll
    for (int kk = 0; kk < N_KK; ++kk) {
        bf16x8 a;
        if (kk < 8) {
            a = *(const bf16x8*)(A + (size_t)nc * 256 + kk * 32 + quad * 8);
        } else {
            if (f32) {
                const float* base = (const float*)x + (size_t)nc * IN_DIM + quad * 8;
                float4 v0 = *(const float4*)base;
                float4 v1 = *(const float4*)(base + 4);
                a[0] = (short)f2bf(v0.x); a[1] = (short)f2bf(v0.y);
                a[2] = (short)f2bf(v0.z); a[3] = (short)f2bf(v0.w);
                a[4] = (short)f2bf(v1.x); a[5] = (short)f2bf(v1.y);
                a[6] = (short)f2bf(v1.z); a[7] = (short)f2bf(v1.w);
            } else {
                a = *(const bf16x8*)((const uint16_t*)x + (size_t)nc * IN_DIM + quad * 8);
            }
        }
        #pragma unroll
        for (int ot = 0; ot < 4; ++ot) {
            bf16x8 b = *(const bf16x8*)(sB + ((kk * 4 + ot) * 64 + lane) * 8);
            acc[ot] = __builtin_amdgcn_mfma_f32_16x16x32_bf16(a, b, acc[ot], 0, 0, 0);
        }
    }

    #pragma unroll
    for (int ot = 0; ot < 4; ++ot) {
        #pragma unroll
        for (int reg = 0; reg < 4; ++reg) {
            int node = n0 + quad * 4 + reg;
            if (node >= N_NODES) continue;
            int o = ot * 16 + m;
            float v = fmaxf(acc[ot][reg] + bias[ot], 0.0f);
            if (f32) ((float*)out)[(size_t)node * OUT_DIM + o] = v;
            else     ((uint16_t*)out)[(size_t)node * OUT_DIM + o] = f2bf(v);
        }
    }
}

// ===========================================================================
extern "C" void kernel_launch(void* const* d_in, const int* in_sizes, int n_in,
                              void* d_out, int out_size, void* d_ws, size_t ws_size,
                              hipStream_t stream) {
    const void* x  = d_in[0];
    const int* el  = (const int*)d_in[1];
    const void* ew = d_in[2];
    const void* Wl = d_in[3];
    const void* bl = d_in[4];
    const void* Ws = d_in[5];
    const void* bs = d_in[6];

    // workspace layout (all 16B-aligned)
    const size_t OFF_HIST  = 64;
    const size_t OFF_BSUM  = OFF_HIST + (size_t)NSEG * 4;        // +3.2MB
    const size_t OFF_EPACK = OFF_BSUM + 1024 * 4;                // +4KB
    const size_t OFF_A     = OFF_EPACK + (size_t)N_EDGES * 8;    // +12.8MB
    const size_t REQ       = OFF_A + (size_t)NSEG * IN_DIM * 2;  // +51.2MB = ~67.2MB
    if (ws_size < REQ) return; // round-4 evidence: ws >= 105.6MB, so never taken

    int*          flag  = (int*)d_ws;
    unsigned int* hist  = (unsigned int*)((char*)d_ws + OFF_HIST);
    unsigned int* bsum  = (unsigned int*)((char*)d_ws + OFF_BSUM);
    uint64_t*     epack = (uint64_t*)((char*)d_ws + OFF_EPACK);
    uint16_t*     A     = (uint16_t*)((char*)d_ws + OFF_A);

    hipMemsetAsync(d_ws, 0, OFF_EPACK, stream);  // flag+hist+bsum only (~3.2MB)
    detect_kernel<<<1, 256, 0, stream>>>((const uint32_t*)x, flag);
    hist_kernel<<<(N_EDGES + 255) / 256, 256, 0, stream>>>(el, hist);
    scanA_kernel<<<NBLK, 256, 0, stream>>>(hist, bsum);
    scanB_kernel<<<1, 256, 0, stream>>>(bsum);
    scanC_kernel<<<(NSEG + 255) / 256, 256, 0, stream>>>(hist, bsum);
    reorder_kernel<<<(N_EDGES + 255) / 256, 256, 0, stream>>>(el, ew, flag, hist, epack);
    accum_kernel<<<NSEG / 8, 256, 0, stream>>>(epack, hist, x, flag, A);
    dense_mfma_kernel<<<(N_NODES + 63) / 64, 256, 0, stream>>>(A, x, Wl, bl, Ws, bs, flag, d_out);
}

// Round 7
// 459.728 us; speedup vs baseline: 1.0185x; 1.0185x over previous
//
#include <hip/hip_runtime.h>
#include <stdint.h>

#define N_NODES 100000
#define N_EDGES 1600000
#define IN_DIM 32
#define OUT_DIM 64
#define N_REL 8
#define NSEG (N_NODES * N_REL)     // 800000
#define EPS 1e-10f
#define N_KK 9                      // K-tiles of 32 (8 rel + 1 self)
#define SCAN_BS 1024                // elems per scan block
#define NBLK ((NSEG + SCAN_BS - 1) / SCAN_BS)  // 782

typedef __attribute__((ext_vector_type(8))) short bf16x8;
typedef __attribute__((ext_vector_type(4))) float f32x4;

static __device__ __forceinline__ float bflo(uint32_t u) { return __uint_as_float(u << 16); }
static __device__ __forceinline__ uint16_t f2bf(float f) {
    uint32_t u = __float_as_uint(f);
    return (uint16_t)((u + 0x7fffu + ((u >> 16) & 1u)) >> 16); // RNE
}

// ---------------------------------------------------------------------------
// Dtype probe (round-3 proved fp32; kept for robustness, ~3us).
// ---------------------------------------------------------------------------
__global__ __launch_bounds__(256) void detect_kernel(const uint32_t* __restrict__ xw,
                                                     int* __restrict__ flag) {
    __shared__ int cnt;
    if (threadIdx.x == 0) cnt = 0;
    __syncthreads();
    int c = 0;
    for (int k = threadIdx.x; k < 4096; k += 256) {
        uint32_t w = xw[k];
        uint32_t e = (w >> 7) & 0xffu;
        c += (e >= 160u) ? 1 : 0;
    }
    atomicAdd(&cnt, c);
    __syncthreads();
    if (threadIdx.x == 0) *flag = (cnt > 64) ? 1 : 0;  // 1 = fp32 inputs
}

// ---------------------------------------------------------------------------
// 1) histogram: hist[dst*8+rel]++
// ---------------------------------------------------------------------------
__global__ __launch_bounds__(256) void hist_kernel(const int* __restrict__ el,
                                                   unsigned int* __restrict__ hist) {
    int e = blockIdx.x * 256 + threadIdx.x;
    if (e >= N_EDGES) return;
    int dst = el[e * 3 + 1];
    int rel = el[e * 3 + 2];
    atomicAdd(&hist[dst * N_REL + rel], 1u);
}

// ---------------------------------------------------------------------------
// 2a) per-block inclusive scan (1024 elems / block), block totals to bsum
// ---------------------------------------------------------------------------
__global__ __launch_bounds__(256) void scanA_kernel(unsigned int* __restrict__ hist,
                                                    unsigned int* __restrict__ bsum) {
    __shared__ unsigned int lds[256];
    int t = threadIdx.x;
    int base = blockIdx.x * SCAN_BS + t * 4;
    unsigned int v[4];
    #pragma unroll
    for (int k = 0; k < 4; ++k) {
        int i = base + k;
        v[k] = (i < NSEG) ? hist[i] : 0u;
    }
    v[1] += v[0]; v[2] += v[1]; v[3] += v[2];   // local inclusive
    lds[t] = v[3];
    __syncthreads();
    unsigned int xv = lds[t];
    for (int off = 1; off < 256; off <<= 1) {
        unsigned int add = (t >= off) ? lds[t - off] : 0u;
        __syncthreads();
        xv += add;
        lds[t] = xv;
        __syncthreads();
    }
    unsigned int excl = (t == 0) ? 0u : lds[t - 1];
    #pragma unroll
    for (int k = 0; k < 4; ++k) {
        int i = base + k;
        if (i < NSEG) hist[i] = excl + v[k];  // block-LOCAL inclusive scan
    }
    if (t == 255) bsum[blockIdx.x] = lds[255];
}

// ---------------------------------------------------------------------------
// 2b) single-block EXCLUSIVE scan of block totals (NBLK <= 1024)
// ---------------------------------------------------------------------------
__global__ __launch_bounds__(256) void scanB_kernel(unsigned int* __restrict__ bsum) {
    __shared__ unsigned int lds[256];
    int t = threadIdx.x;
    int base = t * 4;
    unsigned int v[4];
    #pragma unroll
    for (int k = 0; k < 4; ++k) v[k] = (base + k < NBLK) ? bsum[base + k] : 0u;
    unsigned int l0 = v[0], l1 = l0 + v[1], l2 = l1 + v[2], l3 = l2 + v[3];
    lds[t] = l3;
    __syncthreads();
    unsigned int xv = lds[t];
    for (int off = 1; off < 256; off <<= 1) {
        unsigned int add = (t >= off) ? lds[t - off] : 0u;
        __syncthreads();
        xv += add;
        lds[t] = xv;
        __syncthreads();
    }
    unsigned int excl = (t == 0) ? 0u : lds[t - 1];
    if (base + 0 < NBLK) bsum[base + 0] = excl;
    if (base + 1 < NBLK) bsum[base + 1] = excl + l0;
    if (base + 2 < NBLK) bsum[base + 2] = excl + l1;
    if (base + 3 < NBLK) bsum[base + 3] = excl + l2;
}

// ---------------------------------------------------------------------------
// 3) reorder (scanC fused): global_pos = (--hist[seg] local) + bsum[blk].
//    Destructive sub leaves hist[seg] = LOCAL segment start; accum adds bsum.
// ---------------------------------------------------------------------------
__global__ __launch_bounds__(256) void reorder_kernel(const int* __restrict__ el,
                                                      const void* __restrict__ ew,
                                                      const int* __restrict__ flag,
                                                      unsigned int* __restrict__ hist,
                                                      const unsigned int* __restrict__ bsum,
                                                      uint64_t* __restrict__ epack) {
    int e = blockIdx.x * 256 + threadIdx.x;
    if (e >= N_EDGES) return;
    int src = el[e * 3 + 0];
    int dst = el[e * 3 + 1];
    int rel = el[e * 3 + 2];
    uint32_t wb = (*flag) ? ((const uint32_t*)ew)[e]
                          : (((uint32_t)((const uint16_t*)ew)[e]) << 16);
    int seg = dst * N_REL + rel;
    unsigned int pos = atomicSub(&hist[seg], 1u) - 1u + bsum[seg >> 10];
    epack[pos] = ((uint64_t)wb << 32) | (uint32_t)src;
}

// ---------------------------------------------------------------------------
// 4) accum v2: 32-lane group handles 4 consecutive segments with 4
//    INDEPENDENT accumulation chains (4x memory-level parallelism).
//    A[seg*32+i] = f2bf( sum w*x[src,i] / (sum w + eps) ), pre-divided bf16.
// ---------------------------------------------------------------------------
__global__ __launch_bounds__(256) void accum_kernel(const uint64_t* __restrict__ epack,
                                                    const unsigned int* __restrict__ hist,
                                                    const unsigned int* __restrict__ bsum,
                                                    const void* __restrict__ x,
                                                    const int* __restrict__ flag,
                                                    uint16_t* __restrict__ A) {
    int g = threadIdx.x >> 5;               // group 0..7
    int i = threadIdx.x & 31;               // feature
    int seg0 = (blockIdx.x * 8 + g) * 4;    // 4 segs per group
    int f32 = *flag;

    unsigned int st[5];
    #pragma unroll
    for (int k = 0; k < 5; ++k) {
        int s = seg0 + k;
        st[k] = (s >= NSEG) ? (unsigned int)N_EDGES : hist[s] + bsum[s >> 10];
    }
    int len[4];
    int maxlen = 0;
    #pragma unroll
    for (int k = 0; k < 4; ++k) {
        len[k] = (int)(st[k + 1] - st[k]);
        maxlen = (len[k] > maxlen) ? len[k] : maxlen;
    }

    float acc[4] = {0.f, 0.f, 0.f, 0.f};
    float ws[4]  = {0.f, 0.f, 0.f, 0.f};

    for (int t = 0; t < maxlen; ++t) {
        #pragma unroll
        for (int k = 0; k < 4; ++k) {
            if (t < len[k]) {
                uint64_t p = epack[st[k] + t];
                uint32_t src = (uint32_t)p;
                float w = __uint_as_float((uint32_t)(p >> 32));
                float xv = f32 ? ((const float*)x)[(size_t)src * IN_DIM + i]
                               : bflo((uint32_t)((const uint16_t*)x)[(size_t)src * IN_DIM + i]);
                acc[k] += w * xv;
                ws[k]  += w;
            }
        }
    }
    #pragma unroll
    for (int k = 0; k < 4; ++k)
        A[(size_t)(seg0 + k) * IN_DIM + i] = f2bf(acc[k] / (ws[k] + EPS));
}

// ---------------------------------------------------------------------------
// 5) dense MFMA GEMM: C[100000x64] = [A | x] * [Wl ; Ws]  (round-5 verified)
// ---------------------------------------------------------------------------
__global__ __launch_bounds__(256) void dense_mfma_kernel(
    const uint16_t* __restrict__ A,
    const void* __restrict__ x,
    const void* __restrict__ Wl,
    const void* __restrict__ bl,
    const void* __restrict__ Ws,
    const void* __restrict__ bs,
    const int* __restrict__ flag,
    void* __restrict__ out)
{
    __shared__ uint16_t sB[N_KK * 4 * 64 * 8]; // 18432 bf16 = 36KB
    int f32 = *flag;

    for (int idx = threadIdx.x; idx < N_KK * 4 * 64 * 8; idx += 256) {
        int j    = idx & 7;
        int lane = (idx >> 3) & 63;
        int ot   = (idx >> 9) & 3;
        int kk   = idx >> 11;
        int quad = lane >> 4;
        int k = kk * 32 + quad * 8 + j;
        int o = ot * 16 + (lane & 15);
        if (f32) {
            float v = (k < 256) ? ((const float*)Wl)[(size_t)k * OUT_DIM + o]
                                : ((const float*)Ws)[(size_t)(k - 256) * OUT_DIM + o];
            sB[idx] = f2bf(v);
        } else {
            sB[idx] = (k < 256) ? ((const uint16_t*)Wl)[(size_t)k * OUT_DIM + o]
                                : ((const uint16_t*)Ws)[(size_t)(k - 256) * OUT_DIM + o];
        }
    }
    __syncthreads();

    int wid  = threadIdx.x >> 6;
    int lane = threadIdx.x & 63;
    int quad = lane >> 4;
    int m    = lane & 15;

    int n0 = blockIdx.x * 64 + wid * 16;
    int n  = n0 + m;
    int nc = (n < N_NODES) ? n : (N_NODES - 1);

    float bias[4];
    #pragma unroll
    for (int ot = 0; ot < 4; ++ot) {
        int o = ot * 16 + m;
        if (f32) bias[ot] = ((const float*)bl)[o] + ((const float*)bs)[o];
        else     bias[ot] = bflo((uint32_t)((const uint16_t*)bl)[o])
                          + bflo((uint32_t)((const uint16_t*)bs)[o]);
    }

    f32x4 acc[4];
    #pragma unroll
    for (int ot = 0; ot < 4; ++ot) acc[ot] = (f32x4){0.f, 0.f, 0.f, 0.f};

    #pragma unroll
    for (int kk = 0; kk < N_KK; ++kk) {
        bf16x8 a;
        if (kk < 8) {
            a = *(const bf16x8*)(A + (size_t)nc * 256 + kk * 32 + quad * 8);
        } else {
            if (f32) {
                const float* base = (const float*)x + (size_t)nc * IN_DIM + quad * 8;
                float4 v0 = *(const float4*)base;
                float4 v1 = *(const float4*)(base + 4);
                a[0] = (short)f2bf(v0.x); a[1] = (short)f2bf(v0.y);
                a[2] = (short)f2bf(v0.z); a[3] = (short)f2bf(v0.w);
                a[4] = (short)f2bf(v1.x); a[5] = (short)f2bf(v1.y);
                a[6] = (short)f2bf(v1.z); a[7] = (short)f2bf(v1.w);
            } else {
                a = *(const bf16x8*)((const uint16_t*)x + (size_t)nc * IN_DIM + quad * 8);
            }
        }
        #pragma unroll
        for (int ot = 0; ot < 4; ++ot) {
            bf16x8 b = *(const bf16x8*)(sB + ((kk * 4 + ot) * 64 + lane) * 8);
            acc[ot] = __builtin_amdgcn_mfma_f32_16x16x32_bf16(a, b, acc[ot], 0, 0, 0);
        }
    }

    #pragma unroll
    for (int ot = 0; ot < 4; ++ot) {
        #pragma unroll
        for (int reg = 0; reg < 4; ++reg) {
            int node = n0 + quad * 4 + reg;
            if (node >= N_NODES) continue;
            int o = ot * 16 + m;
            float v = fmaxf(acc[ot][reg] + bias[ot], 0.0f);
            if (f32) ((float*)out)[(size_t)node * OUT_DIM + o] = v;
            else     ((uint16_t*)out)[(size_t)node * OUT_DIM + o] = f2bf(v);
        }
    }
}

// ===========================================================================
extern "C" void kernel_launch(void* const* d_in, const int* in_sizes, int n_in,
                              void* d_out, int out_size, void* d_ws, size_t ws_size,
                              hipStream_t stream) {
    const void* x  = d_in[0];
    const int* el  = (const int*)d_in[1];
    const void* ew = d_in[2];
    const void* Wl = d_in[3];
    const void* bl = d_in[4];
    const void* Ws = d_in[5];
    const void* bs = d_in[6];

    // workspace layout (all 16B-aligned)
    const size_t OFF_HIST  = 64;
    const size_t OFF_BSUM  = OFF_HIST + (size_t)NSEG * 4;        // +3.2MB
    const size_t OFF_EPACK = OFF_BSUM + 1024 * 4;                // +4KB
    const size_t OFF_A     = OFF_EPACK + (size_t)N_EDGES * 8;    // +12.8MB
    const size_t REQ       = OFF_A + (size_t)NSEG * IN_DIM * 2;  // +51.2MB = ~67.2MB
    if (ws_size < REQ) return;

    int*          flag  = (int*)d_ws;
    unsigned int* hist  = (unsigned int*)((char*)d_ws + OFF_HIST);
    unsigned int* bsum  = (unsigned int*)((char*)d_ws + OFF_BSUM);
    uint64_t*     epack = (uint64_t*)((char*)d_ws + OFF_EPACK);
    uint16_t*     A     = (uint16_t*)((char*)d_ws + OFF_A);

    hipMemsetAsync(d_ws, 0, OFF_EPACK, stream);  // flag+hist+bsum (~3.2MB)
    detect_kernel<<<1, 256, 0, stream>>>((const uint32_t*)x, flag);
    hist_kernel<<<(N_EDGES + 255) / 256, 256, 0, stream>>>(el, hist);
    scanA_kernel<<<NBLK, 256, 0, stream>>>(hist, bsum);
    scanB_kernel<<<1, 256, 0, stream>>>(bsum);
    reorder_kernel<<<(N_EDGES + 255) / 256, 256, 0, stream>>>(el, ew, flag, hist, bsum, epack);
    accum_kernel<<<NSEG / 32, 256, 0, stream>>>(epack, hist, bsum, x, flag, A);
    dense_mfma_kernel<<<(N_NODES + 63) / 64, 256, 0, stream>>>(A, x, Wl, bl, Ws, bs, flag, d_out);
}

// Round 8
// 313.601 us; speedup vs baseline: 1.4930x; 1.4660x over previous
//
#include <hip/hip_runtime.h>
#include <stdint.h>

#define N_NODES 100000
#define N_EDGES 1600000
#define IN_DIM 32
#define OUT_DIM 64
#define N_REL 8
#define NSEG (N_NODES * N_REL)     // 800000
#define EPS 1e-10f
#define N_KK 9                      // K-tiles of 32 (8 rel + 1 self)

typedef __attribute__((ext_vector_type(8))) short bf16x8;
typedef __attribute__((ext_vector_type(2))) short bf16x2;
typedef __attribute__((ext_vector_type(4))) float f32x4;

static __device__ __forceinline__ float bflo(uint32_t u) { return __uint_as_float(u << 16); }
static __device__ __forceinline__ float bfhi(uint32_t u) { return __uint_as_float(u & 0xffff0000u); }
static __device__ __forceinline__ uint16_t f2bf(float f) {
    uint32_t u = __float_as_uint(f);
    return (uint16_t)((u + 0x7fffu + ((u >> 16) & 1u)) >> 16); // RNE
}

// Packed bf16x2 atomic add (gfx950 global_atomic_pk_add_bf16); CAS fallback.
static __device__ __forceinline__ void pk_add_bf16(uint32_t* addr, float f0, float f1) {
#if __has_builtin(__builtin_amdgcn_global_atomic_fadd_v2bf16)
    bf16x2 v;
    v[0] = (short)f2bf(f0);
    v[1] = (short)f2bf(f1);
    __builtin_amdgcn_global_atomic_fadd_v2bf16((bf16x2*)addr, v);
#else
    uint32_t old = *addr, assumed;
    do {
        assumed = old;
        float lo = bflo(assumed) + f0;
        float hi = bfhi(assumed) + f1;
        uint32_t nv = (uint32_t)f2bf(lo) | ((uint32_t)f2bf(hi) << 16);
        old = atomicCAS(addr, assumed, nv);
    } while (old != assumed);
#endif
}

// ---------------------------------------------------------------------------
// Dtype probe (round-3 proved fp32; kept for robustness, ~3us).
// ---------------------------------------------------------------------------
__global__ __launch_bounds__(256) void detect_kernel(const uint32_t* __restrict__ xw,
                                                     int* __restrict__ flag) {
    __shared__ int cnt;
    if (threadIdx.x == 0) cnt = 0;
    __syncthreads();
    int c = 0;
    for (int k = threadIdx.x; k < 4096; k += 256) {
        uint32_t w = xw[k];
        uint32_t e = (w >> 7) & 0xffu;
        c += (e >= 160u) ? 1 : 0;
    }
    atomicAdd(&cnt, c);
    __syncthreads();
    if (threadIdx.x == 0) *flag = (cnt > 64) ? 1 : 0;  // 1 = fp32 inputs
}

// ---------------------------------------------------------------------------
// Scatter with packed-bf16 atomics: 16 lanes per edge, lane handles feature
// pair (2i, 2i+1). num[seg][32] bf16: one pk-atomic per lane -> 25.6M atomics
// (half of round-5's 51.2M fp32), one 64B line per edge (was two).
// ---------------------------------------------------------------------------
__global__ __launch_bounds__(256) void scatter_pk_kernel(
    const int* __restrict__ el,
    const void* __restrict__ ew,
    const void* __restrict__ x,
    const int* __restrict__ flag,
    uint32_t* __restrict__ num,   // NSEG * 16 dwords (bf16 pairs)
    float* __restrict__ den)
{
    int t = blockIdx.x * 256 + threadIdx.x;
    int e = t >> 4;
    int p = t & 15;                // feature-pair index
    if (e >= N_EDGES) return;

    int src = el[e * 3 + 0];
    int dst = el[e * 3 + 1];
    int rel = el[e * 3 + 2];
    int f32 = *flag;

    float w = f32 ? ((const float*)ew)[e]
                  : bflo((uint32_t)((const uint16_t*)ew)[e]);

    float x0, x1;
    if (f32) {
        const float2 v = *(const float2*)((const float*)x + (size_t)src * IN_DIM + 2 * p);
        x0 = v.x; x1 = v.y;
    } else {
        uint32_t d = *(const uint32_t*)((const uint16_t*)x + (size_t)src * IN_DIM + 2 * p);
        x0 = bflo(d); x1 = bfhi(d);
    }

    int seg = dst * N_REL + rel;
    pk_add_bf16(&num[(size_t)seg * 16 + p], w * x0, w * x1);
    if (p == 0) atomicAdd(&den[seg], w);
}

// ---------------------------------------------------------------------------
// Dense MFMA GEMM: C[100000x64] = [num/(den+eps) | x] * [Wl ; Ws] + bias, relu
// A-operand kk<8: uint4 load of 8 bf16 from num, unpack * inv, repack.
// MFMA layouts (HW-verified): A[m=lane&15][k=quad*8+j]; B[k][n=lane&15];
// C row=quad*4+reg, col=lane&15.
// ---------------------------------------------------------------------------
__global__ __launch_bounds__(256) void dense_mfma_kernel(
    const uint32_t* __restrict__ num,
    const float* __restrict__ den,
    const void* __restrict__ x,
    const void* __restrict__ Wl,
    const void* __restrict__ bl,
    const void* __restrict__ Ws,
    const void* __restrict__ bs,
    const int* __restrict__ flag,
    void* __restrict__ out)
{
    __shared__ uint16_t sB[N_KK * 4 * 64 * 8]; // 18432 bf16 = 36KB
    int f32 = *flag;

    // stage + swizzle W into b-frag order: sB[kk][ot][lane][j]
    for (int idx = threadIdx.x; idx < N_KK * 4 * 64 * 8; idx += 256) {
        int j    = idx & 7;
        int lane = (idx >> 3) & 63;
        int ot   = (idx >> 9) & 3;
        int kk   = idx >> 11;
        int quad = lane >> 4;
        int k = kk * 32 + quad * 8 + j;
        int o = ot * 16 + (lane & 15);
        if (f32) {
            float v = (k < 256) ? ((const float*)Wl)[(size_t)k * OUT_DIM + o]
                                : ((const float*)Ws)[(size_t)(k - 256) * OUT_DIM + o];
            sB[idx] = f2bf(v);
        } else {
            sB[idx] = (k < 256) ? ((const uint16_t*)Wl)[(size_t)k * OUT_DIM + o]
                                : ((const uint16_t*)Ws)[(size_t)(k - 256) * OUT_DIM + o];
        }
    }
    __syncthreads();

    int wid  = threadIdx.x >> 6;
    int lane = threadIdx.x & 63;
    int quad = lane >> 4;
    int m    = lane & 15;

    int n0 = blockIdx.x * 64 + wid * 16;
    int n  = n0 + m;
    int nc = (n < N_NODES) ? n : (N_NODES - 1);

    float bias[4];
    #pragma unroll
    for (int ot = 0; ot < 4; ++ot) {
        int o = ot * 16 + m;
        if (f32) bias[ot] = ((const float*)bl)[o] + ((const float*)bs)[o];
        else     bias[ot] = bflo((uint32_t)((const uint16_t*)bl)[o])
                          + bflo((uint32_t)((const uint16_t*)bs)[o]);
    }

    f32x4 acc[4];
    #pragma unroll
    for (int ot = 0; ot < 4; ++ot) acc[ot] = (f32x4){0.f, 0.f, 0.f, 0.f};

    #pragma unroll
    for (int kk = 0; kk < N_KK; ++kk) {
        bf16x8 a;
        if (kk < 8) {
            // num dwords: seg*16 + quad*4, seg = nc*8+kk ; 16B-aligned
            const uint4 d = *(const uint4*)(num + ((size_t)nc * 8 + kk) * 16 + quad * 4);
            float inv = 1.0f / (den[(size_t)nc * N_REL + kk] + EPS);
            a[0] = (short)f2bf(bflo(d.x) * inv); a[1] = (short)f2bf(bfhi(d.x) * inv);
            a[2] = (short)f2bf(bflo(d.y) * inv); a[3] = (short)f2bf(bfhi(d.y) * inv);
            a[4] = (short)f2bf(bflo(d.z) * inv); a[5] = (short)f2bf(bfhi(d.z) * inv);
            a[6] = (short)f2bf(bflo(d.w) * inv); a[7] = (short)f2bf(bfhi(d.w) * inv);
        } else {
            if (f32) {
                const float* base = (const float*)x + (size_t)nc * IN_DIM + quad * 8;
                float4 v0 = *(const float4*)base;
                float4 v1 = *(const float4*)(base + 4);
                a[0] = (short)f2bf(v0.x); a[1] = (short)f2bf(v0.y);
                a[2] = (short)f2bf(v0.z); a[3] = (short)f2bf(v0.w);
                a[4] = (short)f2bf(v1.x); a[5] = (short)f2bf(v1.y);
                a[6] = (short)f2bf(v1.z); a[7] = (short)f2bf(v1.w);
            } else {
                a = *(const bf16x8*)((const uint16_t*)x + (size_t)nc * IN_DIM + quad * 8);
            }
        }
        #pragma unroll
        for (int ot = 0; ot < 4; ++ot) {
            bf16x8 b = *(const bf16x8*)(sB + ((kk * 4 + ot) * 64 + lane) * 8);
            acc[ot] = __builtin_amdgcn_mfma_f32_16x16x32_bf16(a, b, acc[ot], 0, 0, 0);
        }
    }

    #pragma unroll
    for (int ot = 0; ot < 4; ++ot) {
        #pragma unroll
        for (int reg = 0; reg < 4; ++reg) {
            int node = n0 + quad * 4 + reg;
            if (node >= N_NODES) continue;
            int o = ot * 16 + m;
            float v = fmaxf(acc[ot][reg] + bias[ot], 0.0f);
            if (f32) ((float*)out)[(size_t)node * OUT_DIM + o] = v;
            else     ((uint16_t*)out)[(size_t)node * OUT_DIM + o] = f2bf(v);
        }
    }
}

// ===========================================================================
extern "C" void kernel_launch(void* const* d_in, const int* in_sizes, int n_in,
                              void* d_out, int out_size, void* d_ws, size_t ws_size,
                              hipStream_t stream) {
    const void* x  = d_in[0];
    const int* el  = (const int*)d_in[1];
    const void* ew = d_in[2];
    const void* Wl = d_in[3];
    const void* bl = d_in[4];
    const void* Ws = d_in[5];
    const void* bs = d_in[6];

    // workspace: [flag 64B][den 3.2MB fp32][num 51.2MB bf16]
    const size_t OFF_DEN = 64;
    const size_t OFF_NUM = OFF_DEN + (size_t)NSEG * 4;
    const size_t REQ     = OFF_NUM + (size_t)NSEG * IN_DIM * 2;  // ~54.6MB
    if (ws_size < REQ) return; // round-4 evidence: ws >= 105.6MB

    int*      flag = (int*)d_ws;
    float*    den  = (float*)((char*)d_ws + OFF_DEN);
    uint32_t* num  = (uint32_t*)((char*)d_ws + OFF_NUM);

    hipMemsetAsync(d_ws, 0, REQ, stream);  // bf16 zero == 0x0000
    detect_kernel<<<1, 256, 0, stream>>>((const uint32_t*)x, flag);
    {
        long long threads = (long long)N_EDGES * 16;
        int blocks = (int)((threads + 255) / 256);  // 100000
        scatter_pk_kernel<<<blocks, 256, 0, stream>>>(el, ew, x, flag, num, den);
    }
    dense_mfma_kernel<<<(N_NODES + 63) / 64, 256, 0, stream>>>(num, den, x, Wl, bl, Ws, bs, flag, d_out);
}

// Round 9
// 276.243 us; speedup vs baseline: 1.6949x; 1.1352x over previous
//
#include <hip/hip_runtime.h>
#include <stdint.h>

#define N_NODES 100000
#define N_EDGES 1600000
#define IN_DIM 32
#define OUT_DIM 64
#define N_REL 8
#define NSEG (N_NODES * N_REL)     // 800000
#define EPS 1e-10f
#define N_KK 9                      // K-tiles of 32 (8 rel + 1 self)
#define SWG_ELEMS (N_KK * 4 * 64 * 8)  // 18432 bf16 in b-frag order

typedef __attribute__((ext_vector_type(8))) short bf16x8;
typedef __attribute__((ext_vector_type(2))) short bf16x2;
typedef __attribute__((ext_vector_type(4))) float f32x4;

static __device__ __forceinline__ float bflo(uint32_t u) { return __uint_as_float(u << 16); }
static __device__ __forceinline__ float bfhi(uint32_t u) { return __uint_as_float(u & 0xffff0000u); }
static __device__ __forceinline__ uint16_t f2bf(float f) {
    uint32_t u = __float_as_uint(f);
    return (uint16_t)((u + 0x7fffu + ((u >> 16) & 1u)) >> 16); // RNE
}

// Packed bf16x2 atomic add (gfx950 global_atomic_pk_add_bf16); CAS fallback.
static __device__ __forceinline__ void pk_add_bf16(uint32_t* addr, float f0, float f1) {
#if __has_builtin(__builtin_amdgcn_global_atomic_fadd_v2bf16)
    bf16x2 v;
    v[0] = (short)f2bf(f0);
    v[1] = (short)f2bf(f1);
    __builtin_amdgcn_global_atomic_fadd_v2bf16((bf16x2*)addr, v);
#else
    uint32_t old = *addr, assumed;
    do {
        assumed = old;
        float lo = bflo(assumed) + f0;
        float hi = bfhi(assumed) + f1;
        uint32_t nv = (uint32_t)f2bf(lo) | ((uint32_t)f2bf(hi) << 16);
        old = atomicCAS(addr, assumed, nv);
    } while (old != assumed);
#endif
}

// ---------------------------------------------------------------------------
// Dtype probe (round-3 proved fp32; kept for robustness, ~3us).
// ---------------------------------------------------------------------------
__global__ __launch_bounds__(256) void detect_kernel(const uint32_t* __restrict__ xw,
                                                     int* __restrict__ flag) {
    __shared__ int cnt;
    if (threadIdx.x == 0) cnt = 0;
    __syncthreads();
    int c = 0;
    for (int k = threadIdx.x; k < 4096; k += 256) {
        uint32_t w = xw[k];
        uint32_t e = (w >> 7) & 0xffu;
        c += (e >= 160u) ? 1 : 0;
    }
    atomicAdd(&cnt, c);
    __syncthreads();
    if (threadIdx.x == 0) *flag = (cnt > 64) ? 1 : 0;  // 1 = fp32 inputs
}

// ---------------------------------------------------------------------------
// prep: swizzle W = [Wl ; Ws] into b-frag order ONCE (was done per dense
// block with 72 uncoalesced scalar reads/thread -> the hidden 135us).
//   sWg[((kk*4+ot)*64+lane)*8+j] = W[kk*32+(lane>>4)*8+j][ot*16+(lane&15)]
// Also fuses bias: biasv[o] = bl[o]+bs[o].
// ---------------------------------------------------------------------------
__global__ __launch_bounds__(256) void prep_kernel(const void* __restrict__ Wl,
                                                   const void* __restrict__ Ws,
                                                   const void* __restrict__ bl,
                                                   const void* __restrict__ bs,
                                                   const int* __restrict__ flag,
                                                   uint16_t* __restrict__ sWg,
                                                   float* __restrict__ biasv) {
    int f32 = *flag;
    int idx = blockIdx.x * 256 + threadIdx.x;
    if (idx < SWG_ELEMS) {
        int j    = idx & 7;
        int lane = (idx >> 3) & 63;
        int ot   = (idx >> 9) & 3;
        int kk   = idx >> 11;
        int quad = lane >> 4;
        int k = kk * 32 + quad * 8 + j;
        int o = ot * 16 + (lane & 15);
        if (f32) {
            float v = (k < 256) ? ((const float*)Wl)[(size_t)k * OUT_DIM + o]
                                : ((const float*)Ws)[(size_t)(k - 256) * OUT_DIM + o];
            sWg[idx] = f2bf(v);
        } else {
            sWg[idx] = (k < 256) ? ((const uint16_t*)Wl)[(size_t)k * OUT_DIM + o]
                                 : ((const uint16_t*)Ws)[(size_t)(k - 256) * OUT_DIM + o];
        }
    } else if (idx < SWG_ELEMS + OUT_DIM) {
        int o = idx - SWG_ELEMS;
        if (f32) biasv[o] = ((const float*)bl)[o] + ((const float*)bs)[o];
        else     biasv[o] = bflo((uint32_t)((const uint16_t*)bl)[o])
                          + bflo((uint32_t)((const uint16_t*)bs)[o]);
    }
}

// ---------------------------------------------------------------------------
// Scatter with packed-bf16 atomics: 16 lanes per edge, lane = feature pair.
// 25.6M pk atomics, one 64B line per edge. Atomic-throughput-bound (~160us).
// ---------------------------------------------------------------------------
__global__ __launch_bounds__(256) void scatter_pk_kernel(
    const int* __restrict__ el,
    const void* __restrict__ ew,
    const void* __restrict__ x,
    const int* __restrict__ flag,
    uint32_t* __restrict__ num,   // NSEG * 16 dwords (bf16 pairs)
    float* __restrict__ den)
{
    int t = blockIdx.x * 256 + threadIdx.x;
    int e = t >> 4;
    int p = t & 15;                // feature-pair index
    if (e >= N_EDGES) return;

    int src = el[e * 3 + 0];
    int dst = el[e * 3 + 1];
    int rel = el[e * 3 + 2];
    int f32 = *flag;

    float w = f32 ? ((const float*)ew)[e]
                  : bflo((uint32_t)((const uint16_t*)ew)[e]);

    float x0, x1;
    if (f32) {
        const float2 v = *(const float2*)((const float*)x + (size_t)src * IN_DIM + 2 * p);
        x0 = v.x; x1 = v.y;
    } else {
        uint32_t d = *(const uint32_t*)((const uint16_t*)x + (size_t)src * IN_DIM + 2 * p);
        x0 = bflo(d); x1 = bfhi(d);
    }

    int seg = dst * N_REL + rel;
    pk_add_bf16(&num[(size_t)seg * 16 + p], w * x0, w * x1);
    if (p == 0) atomicAdd(&den[seg], w);
}

// ---------------------------------------------------------------------------
// Dense MFMA GEMM: C[100000x64] = [num/(den+eps) | x] * W + bias, relu.
// LDS staged from PRE-SWIZZLED sWg with 9 coalesced bf16x8 loads per thread.
// MFMA layouts (HW-verified): A[m=lane&15][k=quad*8+j]; B[k][n=lane&15];
// C row=quad*4+reg, col=lane&15.
// ---------------------------------------------------------------------------
__global__ __launch_bounds__(256) void dense_mfma_kernel(
    const uint32_t* __restrict__ num,
    const float* __restrict__ den,
    const void* __restrict__ x,
    const uint16_t* __restrict__ sWg,
    const float* __restrict__ biasv,
    const int* __restrict__ flag,
    void* __restrict__ out)
{
    __shared__ uint16_t sB[SWG_ELEMS]; // 36KB
    int f32 = *flag;

    #pragma unroll
    for (int it = 0; it < SWG_ELEMS / (256 * 8); ++it) {   // 9 iterations
        int idx = (it * 256 + threadIdx.x) * 8;
        *(bf16x8*)(sB + idx) = *(const bf16x8*)(sWg + idx);
    }
    __syncthreads();

    int wid  = threadIdx.x >> 6;
    int lane = threadIdx.x & 63;
    int quad = lane >> 4;
    int m    = lane & 15;

    int n0 = blockIdx.x * 64 + wid * 16;
    int n  = n0 + m;
    int nc = (n < N_NODES) ? n : (N_NODES - 1);

    float bias[4];
    #pragma unroll
    for (int ot = 0; ot < 4; ++ot) bias[ot] = biasv[ot * 16 + m];

    f32x4 acc[4];
    #pragma unroll
    for (int ot = 0; ot < 4; ++ot) acc[ot] = (f32x4){0.f, 0.f, 0.f, 0.f};

    #pragma unroll
    for (int kk = 0; kk < N_KK; ++kk) {
        bf16x8 a;
        if (kk < 8) {
            const uint4 d = *(const uint4*)(num + ((size_t)nc * 8 + kk) * 16 + quad * 4);
            float inv = 1.0f / (den[(size_t)nc * N_REL + kk] + EPS);
            a[0] = (short)f2bf(bflo(d.x) * inv); a[1] = (short)f2bf(bfhi(d.x) * inv);
            a[2] = (short)f2bf(bflo(d.y) * inv); a[3] = (short)f2bf(bfhi(d.y) * inv);
            a[4] = (short)f2bf(bflo(d.z) * inv); a[5] = (short)f2bf(bfhi(d.z) * inv);
            a[6] = (short)f2bf(bflo(d.w) * inv); a[7] = (short)f2bf(bfhi(d.w) * inv);
        } else {
            if (f32) {
                const float* base = (const float*)x + (size_t)nc * IN_DIM + quad * 8;
                float4 v0 = *(const float4*)base;
                float4 v1 = *(const float4*)(base + 4);
                a[0] = (short)f2bf(v0.x); a[1] = (short)f2bf(v0.y);
                a[2] = (short)f2bf(v0.z); a[3] = (short)f2bf(v0.w);
                a[4] = (short)f2bf(v1.x); a[5] = (short)f2bf(v1.y);
                a[6] = (short)f2bf(v1.z); a[7] = (short)f2bf(v1.w);
            } else {
                a = *(const bf16x8*)((const uint16_t*)x + (size_t)nc * IN_DIM + quad * 8);
            }
        }
        #pragma unroll
        for (int ot = 0; ot < 4; ++ot) {
            bf16x8 b = *(const bf16x8*)(sB + ((kk * 4 + ot) * 64 + lane) * 8);
            acc[ot] = __builtin_amdgcn_mfma_f32_16x16x32_bf16(a, b, acc[ot], 0, 0, 0);
        }
    }

    #pragma unroll
    for (int ot = 0; ot < 4; ++ot) {
        #pragma unroll
        for (int reg = 0; reg < 4; ++reg) {
            int node = n0 + quad * 4 + reg;
            if (node >= N_NODES) continue;
            int o = ot * 16 + m;
            float v = fmaxf(acc[ot][reg] + bias[ot], 0.0f);
            if (f32) ((float*)out)[(size_t)node * OUT_DIM + o] = v;
            else     ((uint16_t*)out)[(size_t)node * OUT_DIM + o] = f2bf(v);
        }
    }
}

// ===========================================================================
extern "C" void kernel_launch(void* const* d_in, const int* in_sizes, int n_in,
                              void* d_out, int out_size, void* d_ws, size_t ws_size,
                              hipStream_t stream) {
    const void* x  = d_in[0];
    const int* el  = (const int*)d_in[1];
    const void* ew = d_in[2];
    const void* Wl = d_in[3];
    const void* bl = d_in[4];
    const void* Ws = d_in[5];
    const void* bs = d_in[6];

    // workspace: [flag 64B][den 3.2MB][num 51.2MB][sWg 36KB][biasv 256B]
    const size_t OFF_DEN  = 64;
    const size_t OFF_NUM  = OFF_DEN + (size_t)NSEG * 4;
    const size_t OFF_SWG  = OFF_NUM + (size_t)NSEG * IN_DIM * 2;
    const size_t OFF_BIAS = OFF_SWG + (size_t)SWG_ELEMS * 2;
    const size_t REQ      = OFF_BIAS + OUT_DIM * 4;  // ~54.6MB
    if (ws_size < REQ) return; // round-4 evidence: ws >= 105.6MB

    int*      flag  = (int*)d_ws;
    float*    den   = (float*)((char*)d_ws + OFF_DEN);
    uint32_t* num   = (uint32_t*)((char*)d_ws + OFF_NUM);
    uint16_t* sWg   = (uint16_t*)((char*)d_ws + OFF_SWG);
    float*    biasv = (float*)((char*)d_ws + OFF_BIAS);

    hipMemsetAsync(d_ws, 0, OFF_SWG, stream);  // flag+den+num (bf16 zero == 0)
    detect_kernel<<<1, 256, 0, stream>>>((const uint32_t*)x, flag);
    prep_kernel<<<(SWG_ELEMS + OUT_DIM + 255) / 256, 256, 0, stream>>>(Wl, Ws, bl, bs, flag, sWg, biasv);
    {
        long long threads = (long long)N_EDGES * 16;
        int blocks = (int)((threads + 255) / 256);  // 100000
        scatter_pk_kernel<<<blocks, 256, 0, stream>>>(el, ew, x, flag, num, den);
    }
    dense_mfma_kernel<<<(N_NODES + 63) / 64, 256, 0, stream>>>(num, den, x, sWg, biasv, flag, d_out);
}